// Round 7
// baseline (1638.688 us; speedup 1.0000x reference)
//
#include <hip/hip_runtime.h>
#include <hip/hip_bf16.h>
#include <cmath>

// ---------------------------------------------------------------------------
// IntegerDiscreteFlow on MI355X (gfx950)
// B=8192, D=1024, d2=512, N=2048, F=8 steps.
// State S (8192x1024 f32) updated in place; the [:, ::-1] reversal is an
// orientation bit (logical j <-> stored 1023-j), flipped each step.
// GEMMs in bf16 MFMA 16x16x32, fp32 accumulate.
// R2: XOR-swizzled LDS placement (bank conflicts -> 0).
// R3/R4: double-buffer -> BK=64; G3 emits next step's A (prep_A once).
// R5: ring-3 LDS pipeline, loads stay in flight across raw s_barrier.
// R6: 128x256 block tile for G1/G2 (32 MFMA per barrier per wave).
// R7: two-iteration DMA lead: step order is waitcnt(NDMA) -> barrier ->
//     ISSUE(c+2) -> COMPUTE(c) with tiles 0,1 pre-issued. Each tile's DMA
//     now has ~2 compute phases (~1400 cyc) to cover ~900 cyc HBM latency.
//     Ring-3 WAR safety: barrier at step c proves COMPUTE(c-1) done, and
//     buf(c+2) == buf(c-1).
// ---------------------------------------------------------------------------

typedef __bf16 bf16_t;
typedef bf16_t bf16x8 __attribute__((ext_vector_type(8)));
typedef float floatx4 __attribute__((ext_vector_type(4)));

#define BQ 8192
#define DD 1024
#define D2 512
#define NH 2048
#define NF 8

__device__ __forceinline__ void gload_lds16(const void* g, void* l) {
    __builtin_amdgcn_global_load_lds(
        (__attribute__((address_space(1))) void*)g,
        (__attribute__((address_space(3))) void*)l, 16, 0, 0);
}

// ---- weight convert+transpose: W (K x N f32, row-major) -> Wt (N x K bf16) --
__global__ __launch_bounds__(256)
void transpose_bf16(const float* __restrict__ W, bf16_t* __restrict__ Wt,
                    int K, int N) {
    __shared__ float tile[32][33];
    size_t fo = (size_t)blockIdx.z * K * N;
    int n0 = blockIdx.x * 32, k0 = blockIdx.y * 32;
    int tx = threadIdx.x & 31, ty = threadIdx.x >> 5;   // 32 x 8
    for (int i = 0; i < 4; i++)
        tile[ty + i*8][tx] = W[fo + (size_t)(k0 + ty + i*8) * N + n0 + tx];
    __syncthreads();
    for (int i = 0; i < 4; i++)
        Wt[fo + (size_t)(n0 + ty + i*8) * K + k0 + tx] = (bf16_t)tile[tx][ty + i*8];
}

// ---- copy x -> S (f32, vectorized) ----
__global__ __launch_bounds__(256)
void copy_x(const float4* __restrict__ x, float4* __restrict__ S) {
    int idx = blockIdx.x * blockDim.x + threadIdx.x;   // 2M threads
    S[idx] = x[idx];
}

// ---- build bf16 A operand (= logical xa) from S, identity orientation ----
__global__ __launch_bounds__(256)
void prep_A(const float* __restrict__ S, bf16_t* __restrict__ Ab) {
    int idx = blockIdx.x * blockDim.x + threadIdx.x;   // over 8192*512
    int m = idx >> 9;
    int j = idx & 511;
    Ab[idx] = (bf16_t)S[(size_t)m * DD + j];
}

// ---- GEMM: C = A(MxK bf16) @ B, B given transposed as Bt (NxK bf16) ----
// Block tile TM x TN, BK=32, ring-3 LDS pipeline with 2-iter DMA lead,
// 4 waves (2x2), wave-tile (TM/2) x (TN/2).
// MODE 0: out = bf16( leaky_relu(acc + bias[n]) )
// MODE 1: S[m, slot(n)] += rint(acc + bias[n]); Abn[m, 511-n] = new value
template<int MODE, int K, int TM, int TN, int MINW>
__global__ __launch_bounds__(256, MINW)
void gemm_kernel(const bf16_t* __restrict__ A, const bf16_t* __restrict__ Bt,
                 const float* __restrict__ bias,
                 bf16_t* __restrict__ Cout, float* __restrict__ S,
                 bf16_t* __restrict__ Abn,
                 int N, int rflag)
{
    constexpr int IM   = TM / 32;          // i-fragments per wave
    constexpr int JN   = TN / 32;          // j-fragments per wave
    constexpr int NA   = TM / 64;          // A DMA instrs per tile
    constexpr int NBD  = TN / 64;          // B DMA instrs per tile
    constexpr int NDMA = NA + NBD;         // DMA instrs per tile
    constexpr int T    = K / 32;           // K-tiles
    constexpr int G    = (T - 1) / 3;      // triple groups covering c=0..T-2
    static_assert((T - 1) % 3 == 0, "pipeline triple-unroll needs (T-1)%3==0");
    static_assert(G >= 2, "need at least two triple groups");
    static_assert(JN % 4 == 0, "bff processed in groups of 4");

    __shared__ __align__(16) bf16_t As[3][TM * 32];
    __shared__ __align__(16) bf16_t Bs[3][TN * 32];

    const int tid  = threadIdx.x;
    const int lane = tid & 63;
    const int wave = tid >> 6;
    const int wm   = wave >> 1;            // 0..1
    const int wn   = wave & 1;             // 0..1
    const int m0   = blockIdx.y * TM;
    const int n0   = blockIdx.x * TN;

    // Staging map (per DMA instr u): thread t -> row u*64 + (t>>2), chunk
    // position p = t&3; global chunk fetched q = p ^ ((row>>1)&3) (XOR
    // swizzle; u*64 doesn't change (row>>1)&3). LDS dst = u*2048 + t*8 elems.
    const int srow = tid >> 2;
    const int sq   = ((tid & 3) ^ ((srow >> 1) & 3)) * 8;
    const bf16_t* agp = A  + (size_t)(m0 + srow) * K + sq;
    const bf16_t* bgp = Bt + (size_t)(n0 + srow) * K + sq;

    floatx4 acc[IM][JN];
#pragma unroll
    for (int i = 0; i < IM; i++)
#pragma unroll
        for (int j = 0; j < JN; j++)
            acc[i][j] = (floatx4){0.f, 0.f, 0.f, 0.f};

    // Fragment read: row rr = base + (lane&15) (base mult. of 16), chunk
    // c = lane>>4 stored at position c ^ ((rr>>1)&3) = c ^ ((lane>>1)&3).
    const int fr  = lane & 15;
    const int fp8 = ((lane >> 4) ^ ((lane >> 1) & 3)) * 8;

#define ISSUE_TILE(NB)                                                       \
    {                                                                        \
        _Pragma("unroll")                                                    \
        for (int u = 0; u < NA; u++)                                         \
            gload_lds16(agp + (size_t)(u*64) * K, &As[NB][u*2048 + tid*8]);  \
        _Pragma("unroll")                                                    \
        for (int u = 0; u < NBD; u++)                                        \
            gload_lds16(bgp + (size_t)(u*64) * K, &Bs[NB][u*2048 + tid*8]);  \
        agp += 32; bgp += 32;                                                \
    }

// bff processed in groups of 4 to cap live registers at JN=8.
#define COMPUTE(CB)                                                          \
    {                                                                        \
        bf16x8 af[IM];                                                       \
        _Pragma("unroll")                                                    \
        for (int i = 0; i < IM; i++)                                         \
            af[i] = *(const bf16x8*)&As[CB][(wm*(TM/2) + i*16 + fr)*32 + fp8];\
        _Pragma("unroll")                                                    \
        for (int g2 = 0; g2 < JN/4; g2++) {                                  \
            bf16x8 bff[4];                                                   \
            _Pragma("unroll")                                                \
            for (int j = 0; j < 4; j++)                                      \
                bff[j] = *(const bf16x8*)                                    \
                    &Bs[CB][(wn*(TN/2) + (g2*4+j)*16 + fr)*32 + fp8];        \
            _Pragma("unroll")                                                \
            for (int i = 0; i < IM; i++)                                     \
                _Pragma("unroll")                                            \
                for (int j = 0; j < 4; j++)                                  \
                    acc[i][g2*4+j] = __builtin_amdgcn_mfma_f32_16x16x32_bf16(\
                                    af[i], bff[j], acc[i][g2*4+j], 0, 0, 0); \
        }                                                                    \
    }

// Step computing tile c (buf CB): prev tile landed (vmcnt <= NDMA: only
// tile c+1's loads may remain), barrier (no drain), then issue tile c+2
// into buf NB == buf(c-1) — WAR-safe because every wave passed the barrier
// having finished COMPUTE(c-1).
#define PIPE_STEP(CB, NB, DO_ISSUE)                                          \
    {                                                                        \
        __builtin_amdgcn_s_waitcnt(0x0F70 | NDMA);                           \
        __builtin_amdgcn_s_barrier();                                        \
        if (DO_ISSUE) ISSUE_TILE(NB);                                        \
        COMPUTE(CB);                                                         \
    }

    // prologue: tiles 0,1 -> bufs 0,1 (2-deep head start)
    ISSUE_TILE(0);
    ISSUE_TILE(1);

    // full groups: c = 3g, 3g+1, 3g+2 computing bufs 0,1,2; issuing c+2
#pragma unroll 1
    for (int g = 0; g < G - 1; ++g) {
        PIPE_STEP(0, 2, true);
        PIPE_STEP(1, 0, true);
        PIPE_STEP(2, 1, true);
    }
    // last group: c = T-4, T-3, T-2; the final issue (tile T) is skipped
    PIPE_STEP(0, 2, true);
    PIPE_STEP(1, 0, true);
    PIPE_STEP(2, 1, false);
    // tail: compute tile T-1, buf (T-1)%3 == 0
    __builtin_amdgcn_s_waitcnt(0x0F70);            // vmcnt(0)
    __builtin_amdgcn_s_barrier();
    COMPUTE(0);

#undef PIPE_STEP
#undef COMPUTE
#undef ISSUE_TILE

    // epilogue: C[row, col], col = lane&15, row = (lane>>4)*4 + r  (m89 layout)
    const int ccol  = lane & 15;
    const int crow4 = (lane >> 4) * 4;
#pragma unroll
    for (int j = 0; j < JN; j++) {
        int col = n0 + wn*(TN/2) + j*16 + ccol;
        float bj = bias[col];
        if (MODE == 0) {
#pragma unroll
            for (int i = 0; i < IM; i++) {
#pragma unroll
                for (int r = 0; r < 4; r++) {
                    int row = m0 + wm*(TM/2) + i*16 + crow4 + r;
                    float v = acc[i][j][r] + bj;
                    v = v >= 0.f ? v : 0.01f * v;
                    Cout[(size_t)row * N + col] = (bf16_t)v;
                }
            }
        } else {
            int slot = rflag ? (511 - col) : (512 + col);
            int aj   = 511 - col;          // next step's xa = reverse(yb)
#pragma unroll
            for (int i = 0; i < IM; i++) {
#pragma unroll
                for (int r = 0; r < 4; r++) {
                    int row = m0 + wm*(TM/2) + i*16 + crow4 + r;
                    float t = acc[i][j][r] + bj;
                    float nv = S[(size_t)row * DD + slot] + rintf(t);
                    S[(size_t)row * DD + slot] = nv;
                    Abn[(size_t)row * D2 + aj] = (bf16_t)nv;
                }
            }
        }
    }
}

// ---- final discretized-logistic NLL reduction ----
__global__ __launch_bounds__(256)
void reduce_nll(const float* __restrict__ S, const float* __restrict__ mean,
                const float* __restrict__ log_scale, float* __restrict__ out)
{
    float local = 0.f;
    const int total = BQ * DD;
    for (int idx = blockIdx.x * blockDim.x + threadIdx.x; idx < total;
         idx += gridDim.x * blockDim.x) {
        int j = idx & (DD - 1);
        float z  = S[idx];
        float mu = mean[j];
        float sc = expf(log_scale[j]);
        float ua = (z + 0.5f - mu) / sc;
        float ub = (z - 0.5f - mu) / sc;
        float la = fminf(ua, 0.f) - log1pf(expf(-fabsf(ua)));
        float lb = fminf(ub, 0.f) - log1pf(expf(-fabsf(ub)));
        float lp = la + logf(1.0f - expf(lb - la) + 1e-8f);
        local += lp;
    }
    __shared__ float red[256];
    red[threadIdx.x] = local;
    __syncthreads();
    for (int s = 128; s > 0; s >>= 1) {
        if (threadIdx.x < s) red[threadIdx.x] += red[threadIdx.x + s];
        __syncthreads();
    }
    if (threadIdx.x == 0) atomicAdd(out, -red[0] * (1.0f / (float)BQ));
}

extern "C" void kernel_launch(void* const* d_in, const int* in_sizes, int n_in,
                              void* d_out, int out_size, void* d_ws, size_t ws_size,
                              hipStream_t stream)
{
    const float* x   = (const float*)d_in[0];
    const float* W1  = (const float*)d_in[1];
    const float* b1  = (const float*)d_in[2];
    const float* W2  = (const float*)d_in[3];
    const float* b2  = (const float*)d_in[4];
    const float* W3  = (const float*)d_in[5];
    const float* b3  = (const float*)d_in[6];
    const float* mean = (const float*)d_in[7];
    const float* lsc  = (const float*)d_in[8];

    char* ws = (char*)d_ws;
    bf16_t* Wt1 = (bf16_t*)ws; ws += (size_t)NF * NH * D2 * 2;   // 16 MB (NxK = 2048x512)
    bf16_t* Wt2 = (bf16_t*)ws; ws += (size_t)NF * NH * NH * 2;   // 64 MB
    bf16_t* Wt3 = (bf16_t*)ws; ws += (size_t)NF * D2 * NH * 2;   // 16 MB (512x2048)
    float*  S   = (float*)ws;  ws += (size_t)BQ * DD * 4;        // 32 MB
    bf16_t* Ab  = (bf16_t*)ws; ws += (size_t)BQ * D2 * 2;        //  8 MB
    bf16_t* H1  = (bf16_t*)ws; ws += (size_t)BQ * NH * 2;        // 32 MB
    bf16_t* H2  = (bf16_t*)ws;                                   // 32 MB  (total 200 MB)

    hipMemsetAsync(d_out, 0, sizeof(float), stream);

    dim3 blk(256);
    // W1: (K=512, N=2048) -> Wt1 (2048x512)
    transpose_bf16<<<dim3(NH/32, D2/32, NF), blk, 0, stream>>>(W1, Wt1, D2, NH);
    // W2: (2048, 2048)
    transpose_bf16<<<dim3(NH/32, NH/32, NF), blk, 0, stream>>>(W2, Wt2, NH, NH);
    // W3: (K=2048, N=512) -> Wt3 (512x2048)
    transpose_bf16<<<dim3(D2/32, NH/32, NF), blk, 0, stream>>>(W3, Wt3, NH, D2);

    copy_x<<<BQ * DD / 4 / 256, blk, 0, stream>>>((const float4*)x, (float4*)S);
    prep_A<<<BQ * D2 / 256, blk, 0, stream>>>(S, Ab);   // step 0 only

    for (int f = 0; f < NF; ++f) {
        int r = f & 1;
        // G1: (8192 x 512) @ (512 x 2048) -> H1   [128x256 tiles, 512 blocks]
        gemm_kernel<0, D2, 128, 256, 2><<<dim3(NH/256, BQ/128), blk, 0, stream>>>(
            Ab, Wt1 + (size_t)f * NH * D2, b1 + (size_t)f * NH, H1, nullptr,
            nullptr, NH, 0);
        // G2: (8192 x 2048) @ (2048 x 2048) -> H2 [128x256 tiles, 512 blocks]
        gemm_kernel<0, NH, 128, 256, 2><<<dim3(NH/256, BQ/128), blk, 0, stream>>>(
            H1, Wt2 + (size_t)f * NH * NH, b2 + (size_t)f * NH, H2, nullptr,
            nullptr, NH, 0);
        // G3: (8192 x 2048) @ (2048 x 512), 64x128 tiles -> S + next-A emit
        gemm_kernel<1, NH, 64, 128, 3><<<dim3(D2/128, BQ/64), blk, 0, stream>>>(
            H2, Wt3 + (size_t)f * D2 * NH, b3 + (size_t)f * D2, nullptr, S,
            Ab, D2, r);
    }

    reduce_nll<<<2048, blk, 0, stream>>>(S, mean, lsc, (float*)d_out);
}